// Round 1
// baseline (446.452 us; speedup 1.0000x reference)
//
#include <hip/hip_runtime.h>

typedef short bf16x8 __attribute__((ext_vector_type(8)));
typedef float f32x4 __attribute__((ext_vector_type(4)));
typedef unsigned short u16;

#define ATT_SCALE 0.08838834764831845f

__device__ __forceinline__ u16 cvt_bf(float f) {
    union { float f; unsigned u; } a; a.f = f;
    unsigned r = a.u + 0x7FFFu + ((a.u >> 16) & 1u);
    return (u16)(r >> 16);
}

__device__ __forceinline__ void gload_lds16(const void* g, void* l) {
    __builtin_amdgcn_global_load_lds(
        (const __attribute__((address_space(1))) unsigned int*)g,
        (__attribute__((address_space(3))) unsigned int*)l, 16, 0, 0);
}

// ---------------- K0: weight prep (permute rows/cols to head-grouped order, cvt bf16, fold BN) ----------------
__global__ __launch_bounds__(256) void k0_prep(
    const float* __restrict__ wqkv, const float* __restrict__ wout,
    const float* __restrict__ wmlp,
    const float* __restrict__ g1, const float* __restrict__ b1,
    const float* __restrict__ m1, const float* __restrict__ v1,
    const float* __restrict__ g2, const float* __restrict__ b2,
    const float* __restrict__ m2, const float* __restrict__ v2,
    u16* __restrict__ W1p, u16* __restrict__ W2p, u16* __restrict__ W3p,
    float* __restrict__ s1, float* __restrict__ t1,
    float* __restrict__ s2, float* __restrict__ t2)
{
    int idx = blockIdx.x * 256 + threadIdx.x;
    if (idx < 786432) {                       // W1p: row o' = part*512 + h*128 + d  <-  orig row part*512 + d*4 + h
        int o = idx >> 9, c = idx & 511;
        int part = o >> 9, wi = o & 511;
        int hh = wi >> 7, dd = wi & 127;
        int orig = part * 512 + dd * 4 + hh;
        W1p[idx] = cvt_bf(wqkv[orig * 512 + c]);
    } else if (idx < 1048576) {               // W2p: col c' = h*128+d  <-  orig col d*4+h
        int j = idx - 786432;
        int o = j >> 9, cp = j & 511;
        int oc = ((cp & 127) << 2) | (cp >> 7);
        W2p[j] = cvt_bf(wout[o * 512 + oc]);
    } else if (idx < 1310720) {
        int j = idx - 1048576;
        W3p[j] = cvt_bf(wmlp[j]);
    } else if (idx < 1311232) {
        int c = idx - 1310720;
        float i1 = g1[c] / sqrtf(v1[c] + 1e-5f);
        s1[c] = i1; t1[c] = b1[c] - m1[c] * i1;
        float i2 = g2[c] / sqrtf(v2[c] + 1e-5f);
        s2[c] = i2; t2[c] = b2[c] - m2[c] * i2;
    }
}

// ---------------- K1: BN1 + depthwise 3x3 + bilinear->7x7, outputs bf16 NHWC ----------------
__global__ __launch_bounds__(256) void k1_bn_dw_bil(
    const float* __restrict__ x, const float* __restrict__ wdw,
    const float* __restrict__ s1, const float* __restrict__ t1,
    u16* __restrict__ ybf, u16* __restrict__ ybil)
{
    __shared__ float xs[32][197];
    __shared__ float ys[32][197];
    __shared__ float wt[32][9];
    __shared__ float sc[32], tc[32];
    int b = blockIdx.x >> 4, cg = blockIdx.x & 15;
    int c0 = cg * 32;
    int t = threadIdx.x;
    if (t < 32) { sc[t] = s1[c0 + t]; tc[t] = t1[c0 + t]; }
    for (int i = t; i < 288; i += 256) wt[i / 9][i % 9] = wdw[(c0 + i / 9) * 9 + i % 9];
    __syncthreads();
    const float* xb = x + ((size_t)b * 512 + c0) * 196;
    for (int i = t; i < 6272; i += 256) {
        int c = i / 196, p = i - c * 196;
        xs[c][p] = xb[i] * sc[c] + tc[c];
    }
    __syncthreads();
    for (int i = t; i < 6272; i += 256) {
        int c = i & 31, p = i >> 5;
        int ii = p / 14, jj = p - ii * 14;
        float acc = 0.f;
        #pragma unroll
        for (int di = -1; di <= 1; ++di) {
            int i2 = ii + di;
            if (i2 < 0 || i2 > 13) continue;
            #pragma unroll
            for (int dj = -1; dj <= 1; ++dj) {
                int j2 = jj + dj;
                if (j2 < 0 || j2 > 13) continue;
                acc += wt[c][(di + 1) * 3 + (dj + 1)] * xs[c][i2 * 14 + j2];
            }
        }
        ys[c][p] = acc;
        ybf[((size_t)b * 196 + p) * 512 + c0 + c] = cvt_bf(acc);
    }
    __syncthreads();
    for (int i = t; i < 1568; i += 256) {     // bilinear(14->7, align_corners) applied pre-pointwise (linear ops commute)
        int c = i & 31, r = i >> 5;
        int ri = r / 7, rj = r - ri * 7;
        float fy = 13.f * ri / 6.f, fx = 13.f * rj / 6.f;
        int y0 = (int)fy; int y1 = min(y0 + 1, 13);
        int x0 = (int)fx; int x1 = min(x0 + 1, 13);
        float wy = fy - y0, wx = fx - x0;
        float v00 = ys[c][y0 * 14 + x0], v01 = ys[c][y0 * 14 + x1];
        float v10 = ys[c][y1 * 14 + x0], v11 = ys[c][y1 * 14 + x1];
        float top = v00 + (v01 - v00) * wx;
        float bot = v10 + (v11 - v10) * wx;
        float r7  = top + (bot - top) * wy;
        ybil[((size_t)b * 49 + r) * 512 + c0 + c] = cvt_bf(r7);
    }
}

// ---------------- GEMM: C[row][col] = sum_k A[row][k]*B[col][k], A/B bf16 K-contig, 128x128 tile, BK=32 ----------------
// EPI 0: plain f32 store [row*ldo+col]
// EPI 1: +x (NCHW) -> resid f32 [row*512+col]; a = relu(bn2(resid)) -> bf16 [row*512+col]
// EPI 2: +resid f32 [row*512+col] -> NCHW f32 store (final output)
template<int EPI>
__global__ __launch_bounds__(256, 2) void gemm_tn(
    const u16* __restrict__ A, const u16* __restrict__ Bw,
    float* __restrict__ out, int ldo,
    const float* __restrict__ auxf, u16* __restrict__ auxb,
    const float* __restrict__ s2, const float* __restrict__ t2)
{
    __shared__ __attribute__((aligned(16))) char smA[8192];
    __shared__ __attribute__((aligned(16))) char smB[8192];
    int t = threadIdx.x;
    int wv = t >> 6, l = t & 63;
    int wr = wv >> 1, wc = wv & 1;
    int m0 = blockIdx.x * 128, n0 = blockIdx.y * 128;
    f32x4 acc[4][4];
    #pragma unroll
    for (int mi = 0; mi < 4; ++mi)
        #pragma unroll
        for (int ni = 0; ni < 4; ++ni)
            acc[mi][ni] = f32x4{0.f, 0.f, 0.f, 0.f};

    const char* Ag = (const char*)A + (size_t)(m0 + (t >> 2)) * 1024 + ((t & 3) << 4);
    const char* Bg = (const char*)Bw + (size_t)(n0 + (t >> 2)) * 1024 + ((t & 3) << 4);
    char* lA = smA + wv * 1024;
    char* lB = smB + wv * 1024;
    int kb = (l >> 4) << 4;
    int rA = wr * 64 + (l & 15);
    int rB = wc * 64 + (l & 15);

    for (int kt = 0; kt < 16; ++kt) {
        __syncthreads();
        gload_lds16(Ag, lA);
        gload_lds16(Ag + 65536, lA + 4096);
        gload_lds16(Bg, lB);
        gload_lds16(Bg + 65536, lB + 4096);
        Ag += 64; Bg += 64;
        __syncthreads();
        bf16x8 af[4], bfr[4];
        #pragma unroll
        for (int mi = 0; mi < 4; ++mi)
            af[mi] = *(const bf16x8*)(smA + (rA + mi * 16) * 64 + kb);
        #pragma unroll
        for (int ni = 0; ni < 4; ++ni)
            bfr[ni] = *(const bf16x8*)(smB + (rB + ni * 16) * 64 + kb);
        #pragma unroll
        for (int mi = 0; mi < 4; ++mi)
            #pragma unroll
            for (int ni = 0; ni < 4; ++ni)
                acc[mi][ni] = __builtin_amdgcn_mfma_f32_16x16x32_bf16(af[mi], bfr[ni], acc[mi][ni], 0, 0, 0);
    }

    #pragma unroll
    for (int mi = 0; mi < 4; ++mi) {
        int rowg = m0 + wr * 64 + mi * 16 + ((l >> 4) << 2);   // 4 consecutive rows; 196%4==0 so never crosses a batch image
        if (EPI == 0) {
            #pragma unroll
            for (int ni = 0; ni < 4; ++ni) {
                int colg = n0 + wc * 64 + ni * 16 + (l & 15);
                float* op = out + (size_t)rowg * ldo + colg;
                #pragma unroll
                for (int v = 0; v < 4; ++v) op[(size_t)v * ldo] = acc[mi][ni][v];
            }
        } else if (EPI == 1) {
            int bb = rowg / 196, pp = rowg - bb * 196;
            #pragma unroll
            for (int ni = 0; ni < 4; ++ni) {
                int colg = n0 + wc * 64 + ni * 16 + (l & 15);
                float4 xv = *(const float4*)(auxf + (size_t)bb * 100352 + (size_t)colg * 196 + pp);
                const float* xa = (const float*)&xv;
                float ss = s2[colg], tt = t2[colg];
                #pragma unroll
                for (int v = 0; v < 4; ++v) {
                    float rv = acc[mi][ni][v] + xa[v];
                    out[(size_t)(rowg + v) * 512 + colg] = rv;
                    float av = rv * ss + tt;
                    av = av > 0.f ? av : 0.f;
                    auxb[(size_t)(rowg + v) * 512 + colg] = cvt_bf(av);
                }
            }
        } else {
            int bb = rowg / 196, pp = rowg - bb * 196;
            #pragma unroll
            for (int ni = 0; ni < 4; ++ni) {
                int colg = n0 + wc * 64 + ni * 16 + (l & 15);
                float4 dv;
                float* da = (float*)&dv;
                #pragma unroll
                for (int v = 0; v < 4; ++v)
                    da[v] = acc[mi][ni][v] + auxf[(size_t)(rowg + v) * 512 + colg];
                *(float4*)(out + (size_t)bb * 100352 + (size_t)colg * 196 + pp) = dv;
            }
        }
    }
}

// ---------------- K4: attention per (b,h): softmax((QK^T + bias)*scale) V ----------------
__global__ __launch_bounds__(256) void k4_attn(
    const float* __restrict__ q, const float* __restrict__ kv7,
    const float* __restrict__ rel, float* __restrict__ O)
{
    __shared__ __attribute__((aligned(16))) float ks[49][130];
    __shared__ __attribute__((aligned(16))) float vs[49][130];
    __shared__ __attribute__((aligned(16))) float qs[4][4][128];
    __shared__ float es[4][4][64];
    int b = blockIdx.x >> 2, h = blockIdx.x & 3;
    int t = threadIdx.x, w = t >> 6, l = t & 63;
    const float* kvb = kv7 + (size_t)b * 49 * 1024 + h * 128;
    for (int i = t; i < 6272; i += 256) {
        int r = i >> 7, d = i & 127;
        ks[r][d] = kvb[r * 1024 + d];
        vs[r][d] = kvb[r * 1024 + 512 + d];
    }
    __syncthreads();
    const float* qb = q + (size_t)b * 196 * 512 + h * 128;
    float* Ob = O + (size_t)b * 196 * 512 + h * 128;
    int jc = l < 49 ? l : 48;
    int kiq = jc / 7, kjq = jc - kiq * 7;
    for (int qd = w; qd < 49; qd += 4) {       // each wave: quads of 4 query rows
        int p0 = qd * 4;
        #pragma unroll
        for (int rr = 0; rr < 4; ++rr) {
            qs[w][rr][l]      = qb[(size_t)(p0 + rr) * 512 + l];
            qs[w][rr][64 + l] = qb[(size_t)(p0 + rr) * 512 + 64 + l];
        }
        float sv0 = 0, sv1 = 0, sv2 = 0, sv3 = 0;
        for (int d2 = 0; d2 < 64; ++d2) {
            float2 kk = *(const float2*)&ks[jc][2 * d2];
            float2 q0 = *(const float2*)&qs[w][0][2 * d2];
            float2 q1 = *(const float2*)&qs[w][1][2 * d2];
            float2 q2 = *(const float2*)&qs[w][2][2 * d2];
            float2 q3 = *(const float2*)&qs[w][3][2 * d2];
            sv0 += q0.x * kk.x + q0.y * kk.y;
            sv1 += q1.x * kk.x + q1.y * kk.y;
            sv2 += q2.x * kk.x + q2.y * kk.y;
            sv3 += q3.x * kk.x + q3.y * kk.y;
        }
        float sv[4] = {sv0, sv1, sv2, sv3};
        float inv[4];
        #pragma unroll
        for (int rr = 0; rr < 4; ++rr) {
            int p = p0 + rr;
            int ih = p / 14, iw = p - ih * 14;
            int qi = ih >> 1, qj = iw >> 1;
            float bias = rel[((qi - kiq + 6) * 13 + (qj - kjq + 6)) * 4 + h];
            float tj = (sv[rr] + bias) * ATT_SCALE;
            if (l >= 49) tj = -3.4e38f;
            float mx = tj;
            #pragma unroll
            for (int o = 32; o >= 1; o >>= 1) mx = fmaxf(mx, __shfl_xor(mx, o));
            float e = (l < 49) ? __expf(tj - mx) : 0.f;
            float den = e;
            #pragma unroll
            for (int o = 32; o >= 1; o >>= 1) den += __shfl_xor(den, o);
            inv[rr] = 1.f / den;
            es[w][rr][l] = e;
        }
        float o0[4] = {0, 0, 0, 0}, o1[4] = {0, 0, 0, 0};
        for (int j2 = 0; j2 < 49; ++j2) {
            float v0 = vs[j2][l], v1 = vs[j2][64 + l];
            #pragma unroll
            for (int rr = 0; rr < 4; ++rr) {
                float ee = es[w][rr][j2];
                o0[rr] += ee * v0;
                o1[rr] += ee * v1;
            }
        }
        #pragma unroll
        for (int rr = 0; rr < 4; ++rr) {
            Ob[(size_t)(p0 + rr) * 512 + l]      = o0[rr] * inv[rr];
            Ob[(size_t)(p0 + rr) * 512 + 64 + l] = o1[rr] * inv[rr];
        }
    }
}

// ---------------- K5: depthwise 3x3 on attention output (NHWC, head-grouped channel order) ----------------
__global__ __launch_bounds__(256) void k5_dw2(
    const float* __restrict__ O, const float* __restrict__ wdw,
    u16* __restrict__ z)
{
    __shared__ float xs[32][197];
    __shared__ float wt[32][9];
    int b = blockIdx.x >> 4, cg = blockIdx.x & 15;
    int c0 = cg * 32;
    int t = threadIdx.x;
    for (int i = t; i < 288; i += 256) {
        int cl = i / 9;
        int cp = c0 + cl;
        int corig = ((cp & 127) << 2) | (cp >> 7);
        wt[cl][i % 9] = wdw[corig * 9 + i % 9];
    }
    const float* Ob = O + (size_t)b * 196 * 512 + c0;
    for (int i = t; i < 6272; i += 256) {
        int c = i & 31, p = i >> 5;
        xs[c][p] = Ob[(size_t)p * 512 + c];
    }
    __syncthreads();
    for (int i = t; i < 6272; i += 256) {
        int c = i & 31, p = i >> 5;
        int ii = p / 14, jj = p - ii * 14;
        float acc = 0.f;
        #pragma unroll
        for (int di = -1; di <= 1; ++di) {
            int i2 = ii + di;
            if (i2 < 0 || i2 > 13) continue;
            #pragma unroll
            for (int dj = -1; dj <= 1; ++dj) {
                int j2 = jj + dj;
                if (j2 < 0 || j2 > 13) continue;
                acc += wt[c][(di + 1) * 3 + (dj + 1)] * xs[c][i2 * 14 + j2];
            }
        }
        z[((size_t)b * 196 + p) * 512 + c0 + c] = cvt_bf(acc);
    }
}

extern "C" void kernel_launch(void* const* d_in, const int* in_sizes, int n_in,
                              void* d_out, int out_size, void* d_ws, size_t ws_size,
                              hipStream_t stream)
{
    const float* x    = (const float*)d_in[0];
    const float* g1   = (const float*)d_in[1];
    const float* b1   = (const float*)d_in[2];
    const float* m1   = (const float*)d_in[3];
    const float* v1   = (const float*)d_in[4];
    const float* wqdw = (const float*)d_in[5];
    const float* wqpw = (const float*)d_in[6];
    const float* rel  = (const float*)d_in[7];
    const float* wodw = (const float*)d_in[8];
    const float* wopw = (const float*)d_in[9];
    const float* g2   = (const float*)d_in[10];
    const float* b2   = (const float*)d_in[11];
    const float* m2   = (const float*)d_in[12];
    const float* v2   = (const float*)d_in[13];
    const float* wmlp = (const float*)d_in[14];

    char* ws = (char*)d_ws;
    size_t off = 0;
    auto alloc = [&](size_t bytes) { char* p = ws + off; off += (bytes + 255) & ~(size_t)255; return p; };
    u16* W1p  = (u16*)alloc(1536ull * 512 * 2);
    u16* W2p  = (u16*)alloc(512ull * 512 * 2);
    u16* W3p  = (u16*)alloc(512ull * 512 * 2);
    float* s1 = (float*)alloc(512 * 4);
    float* t1 = (float*)alloc(512 * 4);
    float* s2 = (float*)alloc(512 * 4);
    float* t2 = (float*)alloc(512 * 4);
    u16* ybf  = (u16*)alloc(25088ull * 512 * 2);   // reused later as abuf
    u16* ybil = (u16*)alloc(6272ull * 512 * 2);
    float* qbuf = (float*)alloc(25088ull * 512 * 4);   // reused later as resid
    float* kv7  = (float*)alloc(6272ull * 1024 * 4);   // reused later as zbuf (bf16)
    float* Obuf = (float*)alloc(25088ull * 512 * 4);
    (void)ws_size; (void)in_sizes; (void)n_in; (void)out_size;

    k0_prep<<<5122, 256, 0, stream>>>(wqpw, wopw, wmlp, g1, b1, m1, v1, g2, b2, m2, v2,
                                      W1p, W2p, W3p, s1, t1, s2, t2);
    k1_bn_dw_bil<<<2048, 256, 0, stream>>>(x, wqdw, s1, t1, ybf, ybil);
    gemm_tn<0><<<dim3(196, 4), 256, 0, stream>>>(ybf, W1p, qbuf, 512, nullptr, nullptr, nullptr, nullptr);
    gemm_tn<0><<<dim3(49, 8), 256, 0, stream>>>(ybil, W1p + 262144, kv7, 1024, nullptr, nullptr, nullptr, nullptr);
    k4_attn<<<512, 256, 0, stream>>>(qbuf, kv7, rel, Obuf);
    u16* zbuf = (u16*)kv7;
    k5_dw2<<<2048, 256, 0, stream>>>(Obuf, wodw, zbuf);
    float* resid = qbuf;
    u16* abuf = ybf;
    gemm_tn<1><<<dim3(196, 4), 256, 0, stream>>>(zbuf, W2p, resid, 512, x, abuf, s2, t2);
    gemm_tn<2><<<dim3(196, 4), 256, 0, stream>>>(abuf, W3p, (float*)d_out, 512, resid, nullptr, nullptr, nullptr);
}

// Round 2
// 376.684 us; speedup vs baseline: 1.1852x; 1.1852x over previous
//
#include <hip/hip_runtime.h>

typedef short bf16x8 __attribute__((ext_vector_type(8)));
typedef float f32x4 __attribute__((ext_vector_type(4)));
typedef unsigned short u16;

#define ATT_SCALE 0.08838834764831845f

__device__ __forceinline__ u16 cvt_bf(float f) {
    union { float f; unsigned u; } a; a.f = f;
    unsigned r = a.u + 0x7FFFu + ((a.u >> 16) & 1u);
    return (u16)(r >> 16);
}

__device__ __forceinline__ void gload_lds16(const void* g, void* l) {
    __builtin_amdgcn_global_load_lds(
        (const __attribute__((address_space(1))) unsigned int*)g,
        (__attribute__((address_space(3))) unsigned int*)l, 16, 0, 0);
}

// ---------------- K0: weight prep (permute rows/cols to head-grouped order, cvt bf16, fold BN) ----------------
__global__ __launch_bounds__(256) void k0_prep(
    const float* __restrict__ wqkv, const float* __restrict__ wout,
    const float* __restrict__ wmlp,
    const float* __restrict__ g1, const float* __restrict__ b1,
    const float* __restrict__ m1, const float* __restrict__ v1,
    const float* __restrict__ g2, const float* __restrict__ b2,
    const float* __restrict__ m2, const float* __restrict__ v2,
    u16* __restrict__ W1p, u16* __restrict__ W2p, u16* __restrict__ W3p,
    float* __restrict__ s1, float* __restrict__ t1,
    float* __restrict__ s2, float* __restrict__ t2)
{
    int idx = blockIdx.x * 256 + threadIdx.x;
    if (idx < 786432) {                       // W1p: row o' = part*512 + h*128 + d  <-  orig row part*512 + d*4 + h
        int o = idx >> 9, c = idx & 511;
        int part = o >> 9, wi = o & 511;
        int hh = wi >> 7, dd = wi & 127;
        int orig = part * 512 + dd * 4 + hh;
        W1p[idx] = cvt_bf(wqkv[orig * 512 + c]);
    } else if (idx < 1048576) {               // W2p: col c' = h*128+d  <-  orig col d*4+h
        int j = idx - 786432;
        int o = j >> 9, cp = j & 511;
        int oc = ((cp & 127) << 2) | (cp >> 7);
        W2p[j] = cvt_bf(wout[o * 512 + oc]);
    } else if (idx < 1310720) {
        int j = idx - 1048576;
        W3p[j] = cvt_bf(wmlp[j]);
    } else if (idx < 1311232) {
        int c = idx - 1310720;
        float i1 = g1[c] / sqrtf(v1[c] + 1e-5f);
        s1[c] = i1; t1[c] = b1[c] - m1[c] * i1;
        float i2 = g2[c] / sqrtf(v2[c] + 1e-5f);
        s2[c] = i2; t2[c] = b2[c] - m2[c] * i2;
    }
}

// ---------------- K1: BN1 + depthwise 3x3 + bilinear->7x7, outputs bf16 NHWC ----------------
__global__ __launch_bounds__(256) void k1_bn_dw_bil(
    const float* __restrict__ x, const float* __restrict__ wdw,
    const float* __restrict__ s1, const float* __restrict__ t1,
    u16* __restrict__ ybf, u16* __restrict__ ybil)
{
    __shared__ float xs[32][197];
    __shared__ float ys[32][197];
    __shared__ float wt[32][9];
    __shared__ float sc[32], tc[32];
    int b = blockIdx.x >> 4, cg = blockIdx.x & 15;
    int c0 = cg * 32;
    int t = threadIdx.x;
    if (t < 32) { sc[t] = s1[c0 + t]; tc[t] = t1[c0 + t]; }
    for (int i = t; i < 288; i += 256) wt[i / 9][i % 9] = wdw[(c0 + i / 9) * 9 + i % 9];
    __syncthreads();
    const float* xb = x + ((size_t)b * 512 + c0) * 196;
    for (int i = t; i < 6272; i += 256) {
        int c = i / 196, p = i - c * 196;
        xs[c][p] = xb[i] * sc[c] + tc[c];
    }
    __syncthreads();
    for (int i = t; i < 6272; i += 256) {
        int c = i & 31, p = i >> 5;
        int ii = p / 14, jj = p - ii * 14;
        float acc = 0.f;
        #pragma unroll
        for (int di = -1; di <= 1; ++di) {
            int i2 = ii + di;
            if (i2 < 0 || i2 > 13) continue;
            #pragma unroll
            for (int dj = -1; dj <= 1; ++dj) {
                int j2 = jj + dj;
                if (j2 < 0 || j2 > 13) continue;
                acc += wt[c][(di + 1) * 3 + (dj + 1)] * xs[c][i2 * 14 + j2];
            }
        }
        ys[c][p] = acc;
        ybf[((size_t)b * 196 + p) * 512 + c0 + c] = cvt_bf(acc);
    }
    __syncthreads();
    for (int i = t; i < 1568; i += 256) {     // bilinear(14->7, align_corners) applied pre-pointwise (linear ops commute)
        int c = i & 31, r = i >> 5;
        int ri = r / 7, rj = r - ri * 7;
        float fy = 13.f * ri / 6.f, fx = 13.f * rj / 6.f;
        int y0 = (int)fy; int y1 = min(y0 + 1, 13);
        int x0 = (int)fx; int x1 = min(x0 + 1, 13);
        float wy = fy - y0, wx = fx - x0;
        float v00 = ys[c][y0 * 14 + x0], v01 = ys[c][y0 * 14 + x1];
        float v10 = ys[c][y1 * 14 + x0], v11 = ys[c][y1 * 14 + x1];
        float top = v00 + (v01 - v00) * wx;
        float bot = v10 + (v11 - v10) * wx;
        float r7  = top + (bot - top) * wy;
        ybil[((size_t)b * 49 + r) * 512 + c0 + c] = cvt_bf(r7);
    }
}

// ---------------- GEMM: C[row][col] = sum_k A[row][k]*B[col][k], A/B bf16 K-contig, 128x128 tile, BK=32 ----------------
// EPI 0: plain f32 store [row*ldo+col]
// EPI 1: +x (NCHW) -> resid f32 [row*512+col]; a = relu(bn2(resid)) -> bf16 [row*512+col]
// EPI 2: +resid f32 [row*512+col] -> NCHW f32 store (final output)
// EPI 3: bf16 store [row*ldo+col] into auxb
template<int EPI>
__global__ __launch_bounds__(256, 2) void gemm_tn(
    const u16* __restrict__ A, const u16* __restrict__ Bw,
    float* __restrict__ out, int ldo,
    const float* __restrict__ auxf, u16* __restrict__ auxb,
    const float* __restrict__ s2, const float* __restrict__ t2)
{
    __shared__ __attribute__((aligned(16))) char smA[8192];
    __shared__ __attribute__((aligned(16))) char smB[8192];
    int t = threadIdx.x;
    int wv = t >> 6, l = t & 63;
    int wr = wv >> 1, wc = wv & 1;
    int m0 = blockIdx.x * 128, n0 = blockIdx.y * 128;
    f32x4 acc[4][4];
    #pragma unroll
    for (int mi = 0; mi < 4; ++mi)
        #pragma unroll
        for (int ni = 0; ni < 4; ++ni)
            acc[mi][ni] = f32x4{0.f, 0.f, 0.f, 0.f};

    const char* Ag = (const char*)A + (size_t)(m0 + (t >> 2)) * 1024 + ((t & 3) << 4);
    const char* Bg = (const char*)Bw + (size_t)(n0 + (t >> 2)) * 1024 + ((t & 3) << 4);
    char* lA = smA + wv * 1024;
    char* lB = smB + wv * 1024;
    int kb = (l >> 4) << 4;
    int rA = wr * 64 + (l & 15);
    int rB = wc * 64 + (l & 15);

    for (int kt = 0; kt < 16; ++kt) {
        __syncthreads();
        gload_lds16(Ag, lA);
        gload_lds16(Ag + 65536, lA + 4096);
        gload_lds16(Bg, lB);
        gload_lds16(Bg + 65536, lB + 4096);
        Ag += 64; Bg += 64;
        __syncthreads();
        bf16x8 af[4], bfr[4];
        #pragma unroll
        for (int mi = 0; mi < 4; ++mi)
            af[mi] = *(const bf16x8*)(smA + (rA + mi * 16) * 64 + kb);
        #pragma unroll
        for (int ni = 0; ni < 4; ++ni)
            bfr[ni] = *(const bf16x8*)(smB + (rB + ni * 16) * 64 + kb);
        #pragma unroll
        for (int mi = 0; mi < 4; ++mi)
            #pragma unroll
            for (int ni = 0; ni < 4; ++ni)
                acc[mi][ni] = __builtin_amdgcn_mfma_f32_16x16x32_bf16(af[mi], bfr[ni], acc[mi][ni], 0, 0, 0);
    }

    #pragma unroll
    for (int mi = 0; mi < 4; ++mi) {
        int rowg = m0 + wr * 64 + mi * 16 + ((l >> 4) << 2);   // 4 consecutive rows; 196%4==0 so never crosses a batch image
        if (EPI == 0) {
            #pragma unroll
            for (int ni = 0; ni < 4; ++ni) {
                int colg = n0 + wc * 64 + ni * 16 + (l & 15);
                float* op = out + (size_t)rowg * ldo + colg;
                #pragma unroll
                for (int v = 0; v < 4; ++v) op[(size_t)v * ldo] = acc[mi][ni][v];
            }
        } else if (EPI == 3) {
            #pragma unroll
            for (int ni = 0; ni < 4; ++ni) {
                int colg = n0 + wc * 64 + ni * 16 + (l & 15);
                #pragma unroll
                for (int v = 0; v < 4; ++v)
                    auxb[(size_t)(rowg + v) * ldo + colg] = cvt_bf(acc[mi][ni][v]);
            }
        } else if (EPI == 1) {
            int bb = rowg / 196, pp = rowg - bb * 196;
            #pragma unroll
            for (int ni = 0; ni < 4; ++ni) {
                int colg = n0 + wc * 64 + ni * 16 + (l & 15);
                float4 xv = *(const float4*)(auxf + (size_t)bb * 100352 + (size_t)colg * 196 + pp);
                const float* xa = (const float*)&xv;
                float ss = s2[colg], tt = t2[colg];
                #pragma unroll
                for (int v = 0; v < 4; ++v) {
                    float rv = acc[mi][ni][v] + xa[v];
                    out[(size_t)(rowg + v) * 512 + colg] = rv;
                    float av = rv * ss + tt;
                    av = av > 0.f ? av : 0.f;
                    auxb[(size_t)(rowg + v) * 512 + colg] = cvt_bf(av);
                }
            }
        } else {
            int bb = rowg / 196, pp = rowg - bb * 196;
            #pragma unroll
            for (int ni = 0; ni < 4; ++ni) {
                int colg = n0 + wc * 64 + ni * 16 + (l & 15);
                float4 dv;
                float* da = (float*)&dv;
                #pragma unroll
                for (int v = 0; v < 4; ++v)
                    da[v] = acc[mi][ni][v] + auxf[(size_t)(rowg + v) * 512 + colg];
                *(float4*)(out + (size_t)bb * 100352 + (size_t)colg * 196 + pp) = dv;
            }
        }
    }
}

// ---------------- K4: MFMA attention per (b,h): softmax((QK^T + bias)*scale) V ----------------
// LDS layout (bytes):
//   [0, 16384)      Kls[64][128] bf16, 16B chunks swizzled: chunk' = chunk ^ (row&15)
//   [16384, 32768)  Vt[128][64]  bf16 (d-major), chunks swizzled: chunk' = chunk ^ (d&7)
//   [32768, 45312)  bias7[49][64] f32 (cols >=49 = -1e30 mask)
//   [45312, 61696)  staging Vtmp[64][128] bf16 (row-major), later per-wave P tiles (2KB each)
#define K4_KLS   0
#define K4_VT    16384
#define K4_BIAS  32768
#define K4_SHR   45312
__global__ __launch_bounds__(256) void k4_attn(
    const u16* __restrict__ qbf, const u16* __restrict__ kvbf,
    const float* __restrict__ rel, float* __restrict__ O)
{
    __shared__ __attribute__((aligned(16))) char sm[61696];
    int b = blockIdx.x >> 2, h = blockIdx.x & 3;
    int t = threadIdx.x, w = t >> 6, l = t & 63;
    const char* kvbase = (const char*)(kvbf + (size_t)b * 49 * 1024 + h * 128);
    // stage K (swizzled) + V (row-major), zero-pad rows 49..63
    for (int id = t; id < 1024; id += 256) {
        int r = id >> 4, c = id & 15;
        uint4 kvv = make_uint4(0, 0, 0, 0), vvv = make_uint4(0, 0, 0, 0);
        if (r < 49) {
            kvv = *(const uint4*)(kvbase + (size_t)r * 2048 + c * 16);
            vvv = *(const uint4*)(kvbase + (size_t)r * 2048 + 1024 + c * 16);
        }
        *(uint4*)(sm + K4_KLS + r * 256 + ((c ^ (r & 15)) * 16)) = kvv;
        *(uint4*)(sm + K4_SHR + r * 256 + c * 16) = vvv;
    }
    float* bias7 = (float*)(sm + K4_BIAS);
    for (int id = t; id < 3136; id += 256) {
        int q7 = id >> 6, j = id & 63;
        float bv = -1e30f;
        if (j < 49) {
            int ki = j / 7, kj = j - ki * 7;
            int qi = q7 / 7, qj = q7 - qi * 7;
            bv = rel[((qi - ki + 6) * 13 + (qj - kj + 6)) * 4 + h];
        }
        bias7[id] = bv;
    }
    __syncthreads();
    // LDS transpose: Vtmp[64][128] -> Vt[128][64] (bf16), lane-consecutive d for conflict-free access
    for (int li = 0; li < 4; ++li) {
        int id = li * 256 + t;
        int d = id & 127, jc = id >> 7;
        u16 vals[8];
        #pragma unroll
        for (int i = 0; i < 8; ++i)
            vals[i] = *(const u16*)(sm + K4_SHR + (jc * 8 + i) * 256 + d * 2);
        *(uint4*)(sm + K4_VT + d * 128 + ((jc ^ (d & 7)) * 16)) = *(uint4*)vals;
    }
    __syncthreads();
    const u16* qb = qbf + (size_t)b * 196 * 512 + h * 128;
    float* Ob = O + (size_t)b * 196 * 512 + h * 128;
    char* Pls = sm + K4_SHR + w * 2048;     // per-wave 16x64 bf16 P tile, chunk ^= (row&7)
    for (int mt = w; mt < 13; mt += 4) {
        int m0 = mt * 16;
        int pa = m0 + (l & 15);
        const u16* qrow = qb + (size_t)pa * 512 + ((l >> 4) << 3);
        bf16x8 qf[4];
        #pragma unroll
        for (int kk = 0; kk < 4; ++kk) {
            bf16x8 z = {0, 0, 0, 0, 0, 0, 0, 0};
            qf[kk] = (pa < 196) ? *(const bf16x8*)(qrow + kk * 32) : z;
        }
        f32x4 s[4];
        #pragma unroll
        for (int nt = 0; nt < 4; ++nt) s[nt] = f32x4{0.f, 0.f, 0.f, 0.f};
        #pragma unroll
        for (int kk = 0; kk < 4; ++kk)
            #pragma unroll
            for (int nt = 0; nt < 4; ++nt) {
                int row = nt * 16 + (l & 15);
                bf16x8 kf = *(const bf16x8*)(sm + K4_KLS + row * 256 + (((kk * 4 + (l >> 4)) ^ (row & 15)) * 16));
                s[nt] = __builtin_amdgcn_mfma_f32_16x16x32_bf16(qf[kk], kf, s[nt], 0, 0, 0);
            }
        // wait for prior iteration's PV reads before overwriting P tile
        asm volatile("s_waitcnt lgkmcnt(0)" ::: "memory");
        float inv[4];
        #pragma unroll
        for (int v = 0; v < 4; ++v) {
            int p = m0 + ((l >> 4) << 2) + v;
            int pc = p < 196 ? p : 195;
            int ih = pc / 14, iw = pc - ih * 14;
            int q7 = (ih >> 1) * 7 + (iw >> 1);
            float sv[4];
            float mx = -3.0e38f;
            #pragma unroll
            for (int nt = 0; nt < 4; ++nt) {
                sv[nt] = (s[nt][v] + bias7[q7 * 64 + nt * 16 + (l & 15)]) * ATT_SCALE;
                mx = fmaxf(mx, sv[nt]);
            }
            #pragma unroll
            for (int o = 8; o >= 1; o >>= 1) mx = fmaxf(mx, __shfl_xor(mx, o));
            float den = 0.f, e[4];
            #pragma unroll
            for (int nt = 0; nt < 4; ++nt) { e[nt] = __expf(sv[nt] - mx); den += e[nt]; }
            #pragma unroll
            for (int o = 8; o >= 1; o >>= 1) den += __shfl_xor(den, o);
            inv[v] = 1.f / den;
            int row = ((l >> 4) << 2) + v;
            #pragma unroll
            for (int nt = 0; nt < 4; ++nt) {
                int col = nt * 16 + (l & 15);
                *(u16*)(Pls + row * 128 + (((col >> 3) ^ (row & 7)) * 16) + ((col & 7) * 2)) = cvt_bf(e[nt]);
            }
        }
        asm volatile("s_waitcnt lgkmcnt(0)" ::: "memory");
        __builtin_amdgcn_sched_barrier(0);
        f32x4 o[8];
        #pragma unroll
        for (int nt2 = 0; nt2 < 8; ++nt2) o[nt2] = f32x4{0.f, 0.f, 0.f, 0.f};
        #pragma unroll
        for (int kk = 0; kk < 2; ++kk) {
            int rowp = l & 15;
            bf16x8 pf = *(const bf16x8*)(Pls + rowp * 128 + (((kk * 4 + (l >> 4)) ^ (rowp & 7)) * 16));
            #pragma unroll
            for (int nt2 = 0; nt2 < 8; ++nt2) {
                int d = nt2 * 16 + (l & 15);
                bf16x8 vf = *(const bf16x8*)(sm + K4_VT + d * 128 + (((kk * 4 + (l >> 4)) ^ (d & 7)) * 16));
                o[nt2] = __builtin_amdgcn_mfma_f32_16x16x32_bf16(pf, vf, o[nt2], 0, 0, 0);
            }
        }
        #pragma unroll
        for (int nt2 = 0; nt2 < 8; ++nt2) {
            #pragma unroll
            for (int v = 0; v < 4; ++v) {
                int p = m0 + ((l >> 4) << 2) + v;
                if (p < 196)
                    Ob[(size_t)p * 512 + nt2 * 16 + (l & 15)] = o[nt2][v] * inv[v];
            }
        }
    }
}

// ---------------- K5: depthwise 3x3 on attention output (NHWC, head-grouped channel order) ----------------
__global__ __launch_bounds__(256) void k5_dw2(
    const float* __restrict__ O, const float* __restrict__ wdw,
    u16* __restrict__ z)
{
    __shared__ float xs[32][197];
    __shared__ float wt[32][9];
    int b = blockIdx.x >> 4, cg = blockIdx.x & 15;
    int c0 = cg * 32;
    int t = threadIdx.x;
    for (int i = t; i < 288; i += 256) {
        int cl = i / 9;
        int cp = c0 + cl;
        int corig = ((cp & 127) << 2) | (cp >> 7);
        wt[cl][i % 9] = wdw[corig * 9 + i % 9];
    }
    const float* Ob = O + (size_t)b * 196 * 512 + c0;
    for (int i = t; i < 6272; i += 256) {
        int c = i & 31, p = i >> 5;
        xs[c][p] = Ob[(size_t)p * 512 + c];
    }
    __syncthreads();
    for (int i = t; i < 6272; i += 256) {
        int c = i & 31, p = i >> 5;
        int ii = p / 14, jj = p - ii * 14;
        float acc = 0.f;
        #pragma unroll
        for (int di = -1; di <= 1; ++di) {
            int i2 = ii + di;
            if (i2 < 0 || i2 > 13) continue;
            #pragma unroll
            for (int dj = -1; dj <= 1; ++dj) {
                int j2 = jj + dj;
                if (j2 < 0 || j2 > 13) continue;
                acc += wt[c][(di + 1) * 3 + (dj + 1)] * xs[c][i2 * 14 + j2];
            }
        }
        z[((size_t)b * 196 + p) * 512 + c0 + c] = cvt_bf(acc);
    }
}

extern "C" void kernel_launch(void* const* d_in, const int* in_sizes, int n_in,
                              void* d_out, int out_size, void* d_ws, size_t ws_size,
                              hipStream_t stream)
{
    const float* x    = (const float*)d_in[0];
    const float* g1   = (const float*)d_in[1];
    const float* b1   = (const float*)d_in[2];
    const float* m1   = (const float*)d_in[3];
    const float* v1   = (const float*)d_in[4];
    const float* wqdw = (const float*)d_in[5];
    const float* wqpw = (const float*)d_in[6];
    const float* rel  = (const float*)d_in[7];
    const float* wodw = (const float*)d_in[8];
    const float* wopw = (const float*)d_in[9];
    const float* g2   = (const float*)d_in[10];
    const float* b2   = (const float*)d_in[11];
    const float* m2   = (const float*)d_in[12];
    const float* v2   = (const float*)d_in[13];
    const float* wmlp = (const float*)d_in[14];

    char* ws = (char*)d_ws;
    size_t off = 0;
    auto alloc = [&](size_t bytes) { char* p = ws + off; off += (bytes + 255) & ~(size_t)255; return p; };
    u16* W1p  = (u16*)alloc(1536ull * 512 * 2);
    u16* W2p  = (u16*)alloc(512ull * 512 * 2);
    u16* W3p  = (u16*)alloc(512ull * 512 * 2);
    float* s1 = (float*)alloc(512 * 4);
    float* t1 = (float*)alloc(512 * 4);
    float* s2 = (float*)alloc(512 * 4);
    float* t2 = (float*)alloc(512 * 4);
    u16* ybf  = (u16*)alloc(25088ull * 512 * 2);   // reused later as abuf
    u16* ybil = (u16*)alloc(6272ull * 512 * 2);
    float* qbuf = (float*)alloc(25088ull * 512 * 4);   // holds qbf (bf16), reused later as resid f32
    float* kv7  = (float*)alloc(6272ull * 1024 * 4);   // holds kvbf (bf16), reused later as zbuf (bf16)
    float* Obuf = (float*)alloc(25088ull * 512 * 4);
    (void)ws_size; (void)in_sizes; (void)n_in; (void)out_size;

    u16* qbf  = (u16*)qbuf;
    u16* kvbf = (u16*)kv7;

    k0_prep<<<5122, 256, 0, stream>>>(wqpw, wopw, wmlp, g1, b1, m1, v1, g2, b2, m2, v2,
                                      W1p, W2p, W3p, s1, t1, s2, t2);
    k1_bn_dw_bil<<<2048, 256, 0, stream>>>(x, wqdw, s1, t1, ybf, ybil);
    gemm_tn<3><<<dim3(196, 4), 256, 0, stream>>>(ybf, W1p, nullptr, 512, nullptr, qbf, nullptr, nullptr);
    gemm_tn<3><<<dim3(49, 8), 256, 0, stream>>>(ybil, W1p + 262144, nullptr, 1024, nullptr, kvbf, nullptr, nullptr);
    k4_attn<<<512, 256, 0, stream>>>(qbf, kvbf, rel, Obuf);
    u16* zbuf = (u16*)kv7;
    k5_dw2<<<2048, 256, 0, stream>>>(Obuf, wodw, zbuf);
    float* resid = qbuf;
    u16* abuf = ybf;
    gemm_tn<1><<<dim3(196, 4), 256, 0, stream>>>(zbuf, W2p, resid, 512, x, abuf, s2, t2);
    gemm_tn<2><<<dim3(196, 4), 256, 0, stream>>>(abuf, W3p, (float*)d_out, 512, resid, nullptr, nullptr, nullptr);
}

// Round 6
// 358.754 us; speedup vs baseline: 1.2445x; 1.0500x over previous
//
#include <hip/hip_runtime.h>

typedef short bf16x8 __attribute__((ext_vector_type(8)));
typedef float f32x4 __attribute__((ext_vector_type(4)));
typedef unsigned short u16;

#define ATT_SCALE 0.08838834764831845f

__device__ __forceinline__ u16 cvt_bf(float f) {
    union { float f; unsigned u; } a; a.f = f;
    unsigned r = a.u + 0x7FFFu + ((a.u >> 16) & 1u);
    return (u16)(r >> 16);
}

__device__ __forceinline__ float bf2f(u16 h) {
    union { unsigned u; float f; } a; a.u = ((unsigned)h) << 16;
    return a.f;
}

__device__ __forceinline__ void gload_lds16(const void* g, void* l) {
    __builtin_amdgcn_global_load_lds(
        (const __attribute__((address_space(1))) unsigned int*)g,
        (__attribute__((address_space(3))) unsigned int*)l, 16, 0, 0);
}

// ---------------- K0: weight prep (permute rows/cols to head-grouped order, cvt bf16, fold BN) ----------------
__global__ __launch_bounds__(256) void k0_prep(
    const float* __restrict__ wqkv, const float* __restrict__ wout,
    const float* __restrict__ wmlp,
    const float* __restrict__ g1, const float* __restrict__ b1,
    const float* __restrict__ m1, const float* __restrict__ v1,
    const float* __restrict__ g2, const float* __restrict__ b2,
    const float* __restrict__ m2, const float* __restrict__ v2,
    u16* __restrict__ W1p, u16* __restrict__ W2p, u16* __restrict__ W3p,
    float* __restrict__ s1, float* __restrict__ t1,
    float* __restrict__ s2, float* __restrict__ t2)
{
    int idx = blockIdx.x * 256 + threadIdx.x;
    if (idx < 786432) {                       // W1p: row o' = part*512 + h*128 + d  <-  orig row part*512 + d*4 + h
        int o = idx >> 9, c = idx & 511;
        int part = o >> 9, wi = o & 511;
        int hh = wi >> 7, dd = wi & 127;
        int orig = part * 512 + dd * 4 + hh;
        W1p[idx] = cvt_bf(wqkv[orig * 512 + c]);
    } else if (idx < 1048576) {               // W2p: col c' = h*128+d  <-  orig col d*4+h
        int j = idx - 786432;
        int o = j >> 9, cp = j & 511;
        int oc = ((cp & 127) << 2) | (cp >> 7);
        W2p[j] = cvt_bf(wout[o * 512 + oc]);
    } else if (idx < 1310720) {
        int j = idx - 1048576;
        W3p[j] = cvt_bf(wmlp[j]);
    } else if (idx < 1311232) {
        int c = idx - 1310720;
        float i1 = g1[c] / sqrtf(v1[c] + 1e-5f);
        s1[c] = i1; t1[c] = b1[c] - m1[c] * i1;
        float i2 = g2[c] / sqrtf(v2[c] + 1e-5f);
        s2[c] = i2; t2[c] = b2[c] - m2[c] * i2;
    }
}

// ---------------- K1: BN1 + depthwise 3x3 + bilinear->7x7, outputs bf16 NHWC ----------------
// bf16 LDS tiles (stride 199 u16) -> 27KB LDS -> 5 blocks/CU (was 52KB -> 3)
__global__ __launch_bounds__(256) void k1_bn_dw_bil(
    const float* __restrict__ x, const float* __restrict__ wdw,
    const float* __restrict__ s1, const float* __restrict__ t1,
    u16* __restrict__ ybf, u16* __restrict__ ybil)
{
    __shared__ u16 xs[32][199];
    __shared__ u16 ys[32][199];
    __shared__ float wt[32][9];
    __shared__ float sc[32], tc[32];
    int b = blockIdx.x >> 4, cg = blockIdx.x & 15;
    int c0 = cg * 32;
    int t = threadIdx.x;
    if (t < 32) { sc[t] = s1[c0 + t]; tc[t] = t1[c0 + t]; }
    for (int i = t; i < 288; i += 256) wt[i / 9][i % 9] = wdw[(c0 + i / 9) * 9 + i % 9];
    __syncthreads();
    const float4* xb4 = (const float4*)(x + ((size_t)b * 512 + c0) * 196);
    for (int i = t; i < 1568; i += 256) {     // element index = 4*i (196 % 4 == 0: float4 never crosses channel)
        int c = i / 49, j = i - c * 49;
        float4 v = xb4[i];
        float ss = sc[c], tt = tc[c];
        xs[c][4 * j]     = cvt_bf(v.x * ss + tt);
        xs[c][4 * j + 1] = cvt_bf(v.y * ss + tt);
        xs[c][4 * j + 2] = cvt_bf(v.z * ss + tt);
        xs[c][4 * j + 3] = cvt_bf(v.w * ss + tt);
    }
    __syncthreads();
    for (int i = t; i < 6272; i += 256) {
        int c = i & 31, p = i >> 5;
        int ii = p / 14, jj = p - ii * 14;
        float acc = 0.f;
        #pragma unroll
        for (int di = -1; di <= 1; ++di) {
            int i2 = ii + di;
            if (i2 < 0 || i2 > 13) continue;
            #pragma unroll
            for (int dj = -1; dj <= 1; ++dj) {
                int j2 = jj + dj;
                if (j2 < 0 || j2 > 13) continue;
                acc += wt[c][(di + 1) * 3 + (dj + 1)] * bf2f(xs[c][i2 * 14 + j2]);
            }
        }
        u16 ab = cvt_bf(acc);
        ys[c][p] = ab;
        ybf[((size_t)b * 196 + p) * 512 + c0 + c] = ab;
    }
    __syncthreads();
    for (int i = t; i < 1568; i += 256) {     // bilinear(14->7, align_corners) applied pre-pointwise (linear ops commute)
        int c = i & 31, r = i >> 5;
        int ri = r / 7, rj = r - ri * 7;
        float fy = 13.f * ri / 6.f, fx = 13.f * rj / 6.f;
        int y0 = (int)fy; int y1 = min(y0 + 1, 13);
        int x0 = (int)fx; int x1 = min(x0 + 1, 13);
        float wy = fy - y0, wx = fx - x0;
        float v00 = bf2f(ys[c][y0 * 14 + x0]), v01 = bf2f(ys[c][y0 * 14 + x1]);
        float v10 = bf2f(ys[c][y1 * 14 + x0]), v11 = bf2f(ys[c][y1 * 14 + x1]);
        float top = v00 + (v01 - v00) * wx;
        float bot = v10 + (v11 - v10) * wx;
        float r7  = top + (bot - top) * wy;
        ybil[((size_t)b * 49 + r) * 512 + c0 + c] = cvt_bf(r7);
    }
}

// ---------------- GEMM: C[row][col] = sum_k A[row][k]*B[col][k], A/B bf16 K-contig, 128x128 tile, BK=32 ----------------
// EPI 0: plain f32 store [row*ldo+col]
// EPI 1: +x (NCHW) -> resid f32 [row*512+col]; a = relu(bn2(resid)) -> bf16 [row*512+col]
// EPI 2: +resid f32 [row*512+col] -> NCHW f32 store (final output)
// EPI 3: bf16 store [row*ldo+col] into auxb
template<int EPI>
__global__ __launch_bounds__(256, 2) void gemm_tn(
    const u16* __restrict__ A, const u16* __restrict__ Bw,
    float* __restrict__ out, int ldo,
    const float* __restrict__ auxf, u16* __restrict__ auxb,
    const float* __restrict__ s2, const float* __restrict__ t2)
{
    __shared__ __attribute__((aligned(16))) char smA[8192];
    __shared__ __attribute__((aligned(16))) char smB[8192];
    int t = threadIdx.x;
    int wv = t >> 6, l = t & 63;
    int wr = wv >> 1, wc = wv & 1;
    int m0 = blockIdx.x * 128, n0 = blockIdx.y * 128;
    f32x4 acc[4][4];
    #pragma unroll
    for (int mi = 0; mi < 4; ++mi)
        #pragma unroll
        for (int ni = 0; ni < 4; ++ni)
            acc[mi][ni] = f32x4{0.f, 0.f, 0.f, 0.f};

    const char* Ag = (const char*)A + (size_t)(m0 + (t >> 2)) * 1024 + ((t & 3) << 4);
    const char* Bg = (const char*)Bw + (size_t)(n0 + (t >> 2)) * 1024 + ((t & 3) << 4);
    char* lA = smA + wv * 1024;
    char* lB = smB + wv * 1024;
    int kb = (l >> 4) << 4;
    int rA = wr * 64 + (l & 15);
    int rB = wc * 64 + (l & 15);

    for (int kt = 0; kt < 16; ++kt) {
        __syncthreads();
        gload_lds16(Ag, lA);
        gload_lds16(Ag + 65536, lA + 4096);
        gload_lds16(Bg, lB);
        gload_lds16(Bg + 65536, lB + 4096);
        Ag += 64; Bg += 64;
        __syncthreads();
        bf16x8 af[4], bfr[4];
        #pragma unroll
        for (int mi = 0; mi < 4; ++mi)
            af[mi] = *(const bf16x8*)(smA + (rA + mi * 16) * 64 + kb);
        #pragma unroll
        for (int ni = 0; ni < 4; ++ni)
            bfr[ni] = *(const bf16x8*)(smB + (rB + ni * 16) * 64 + kb);
        #pragma unroll
        for (int mi = 0; mi < 4; ++mi)
            #pragma unroll
            for (int ni = 0; ni < 4; ++ni)
                acc[mi][ni] = __builtin_amdgcn_mfma_f32_16x16x32_bf16(af[mi], bfr[ni], acc[mi][ni], 0, 0, 0);
    }

    #pragma unroll
    for (int mi = 0; mi < 4; ++mi) {
        int rowg = m0 + wr * 64 + mi * 16 + ((l >> 4) << 2);   // 4 consecutive rows; 196%4==0 so never crosses a batch image
        if (EPI == 0) {
            #pragma unroll
            for (int ni = 0; ni < 4; ++ni) {
                int colg = n0 + wc * 64 + ni * 16 + (l & 15);
                float* op = out + (size_t)rowg * ldo + colg;
                #pragma unroll
                for (int v = 0; v < 4; ++v) op[(size_t)v * ldo] = acc[mi][ni][v];
            }
        } else if (EPI == 3) {
            #pragma unroll
            for (int ni = 0; ni < 4; ++ni) {
                int colg = n0 + wc * 64 + ni * 16 + (l & 15);
                #pragma unroll
                for (int v = 0; v < 4; ++v)
                    auxb[(size_t)(rowg + v) * ldo + colg] = cvt_bf(acc[mi][ni][v]);
            }
        } else if (EPI == 1) {
            int bb = rowg / 196, pp = rowg - bb * 196;
            #pragma unroll
            for (int ni = 0; ni < 4; ++ni) {
                int colg = n0 + wc * 64 + ni * 16 + (l & 15);
                float4 xv = *(const float4*)(auxf + (size_t)bb * 100352 + (size_t)colg * 196 + pp);
                const float* xa = (const float*)&xv;
                float ss = s2[colg], tt = t2[colg];
                #pragma unroll
                for (int v = 0; v < 4; ++v) {
                    float rv = acc[mi][ni][v] + xa[v];
                    out[(size_t)(rowg + v) * 512 + colg] = rv;
                    float av = rv * ss + tt;
                    av = av > 0.f ? av : 0.f;
                    auxb[(size_t)(rowg + v) * 512 + colg] = cvt_bf(av);
                }
            }
        } else {
            int bb = rowg / 196, pp = rowg - bb * 196;
            #pragma unroll
            for (int ni = 0; ni < 4; ++ni) {
                int colg = n0 + wc * 64 + ni * 16 + (l & 15);
                float4 dv;
                float* da = (float*)&dv;
                #pragma unroll
                for (int v = 0; v < 4; ++v)
                    da[v] = acc[mi][ni][v] + auxf[(size_t)(rowg + v) * 512 + colg];
                *(float4*)(out + (size_t)bb * 100352 + (size_t)colg * 196 + pp) = dv;
            }
        }
    }
}

// ---------------- K4: MFMA attention per (b,h): softmax((QK^T + bias)*scale) V, bf16 O output ----------------
// LDS layout (bytes):
//   [0, 16384)      Kls[64][128] bf16, 16B chunks swizzled: chunk' = chunk ^ (row&15)
//   [16384, 32768)  Vt[128][64]  bf16 (d-major), chunks swizzled: chunk' = chunk ^ (d&7)
//   [32768, 45312)  bias7[49][64] f32 (cols >=49 = -1e30 mask)
//   [45312, 61696)  staging Vtmp[64][128] bf16 (row-major), later per-wave P tiles (2KB each)
#define K4_KLS   0
#define K4_VT    16384
#define K4_BIAS  32768
#define K4_SHR   45312
__global__ __launch_bounds__(256) void k4_attn(
    const u16* __restrict__ qbf, const u16* __restrict__ kvbf,
    const float* __restrict__ rel, u16* __restrict__ O)
{
    __shared__ __attribute__((aligned(16))) char sm[61696];
    int b = blockIdx.x >> 2, h = blockIdx.x & 3;
    int t = threadIdx.x, w = t >> 6, l = t & 63;
    const char* kvbase = (const char*)(kvbf + (size_t)b * 49 * 1024 + h * 128);
    // stage K (swizzled) + V (row-major), zero-pad rows 49..63
    for (int id = t; id < 1024; id += 256) {
        int r = id >> 4, c = id & 15;
        uint4 kvv = make_uint4(0, 0, 0, 0), vvv = make_uint4(0, 0, 0, 0);
        if (r < 49) {
            kvv = *(const uint4*)(kvbase + (size_t)r * 2048 + c * 16);
            vvv = *(const uint4*)(kvbase + (size_t)r * 2048 + 1024 + c * 16);
        }
        *(uint4*)(sm + K4_KLS + r * 256 + ((c ^ (r & 15)) * 16)) = kvv;
        *(uint4*)(sm + K4_SHR + r * 256 + c * 16) = vvv;
    }
    float* bias7 = (float*)(sm + K4_BIAS);
    for (int id = t; id < 3136; id += 256) {
        int q7 = id >> 6, j = id & 63;
        float bv = -1e30f;
        if (j < 49) {
            int ki = j / 7, kj = j - ki * 7;
            int qi = q7 / 7, qj = q7 - qi * 7;
            bv = rel[((qi - ki + 6) * 13 + (qj - kj + 6)) * 4 + h];
        }
        bias7[id] = bv;
    }
    __syncthreads();
    // LDS transpose: Vtmp[64][128] -> Vt[128][64] (bf16), lane-consecutive d for conflict-free access
    for (int li = 0; li < 4; ++li) {
        int id = li * 256 + t;
        int d = id & 127, jc = id >> 7;
        u16 vals[8];
        #pragma unroll
        for (int i = 0; i < 8; ++i)
            vals[i] = *(const u16*)(sm + K4_SHR + (jc * 8 + i) * 256 + d * 2);
        *(uint4*)(sm + K4_VT + d * 128 + ((jc ^ (d & 7)) * 16)) = *(uint4*)vals;
    }
    __syncthreads();
    const u16* qb = qbf + (size_t)b * 196 * 512 + h * 128;
    u16* Ob = O + (size_t)b * 196 * 512 + h * 128;
    char* Pls = sm + K4_SHR + w * 2048;     // per-wave 16x64 bf16 P tile, chunk ^= (row&7)
    for (int mt = w; mt < 13; mt += 4) {
        int m0 = mt * 16;
        int pa = m0 + (l & 15);
        const u16* qrow = qb + (size_t)pa * 512 + ((l >> 4) << 3);
        bf16x8 qf[4];
        #pragma unroll
        for (int kk = 0; kk < 4; ++kk) {
            bf16x8 z = {0, 0, 0, 0, 0, 0, 0, 0};
            qf[kk] = (pa < 196) ? *(const bf16x8*)(qrow + kk * 32) : z;
        }
        f32x4 s[4];
        #pragma unroll
        for (int nt = 0; nt < 4; ++nt) s[nt] = f32x4{0.f, 0.f, 0.f, 0.f};
        #pragma unroll
        for (int kk = 0; kk < 4; ++kk)
            #pragma unroll
            for (int nt = 0; nt < 4; ++nt) {
                int row = nt * 16 + (l & 15);
                bf16x8 kf = *(const bf16x8*)(sm + K4_KLS + row * 256 + (((kk * 4 + (l >> 4)) ^ (row & 15)) * 16));
                s[nt] = __builtin_amdgcn_mfma_f32_16x16x32_bf16(qf[kk], kf, s[nt], 0, 0, 0);
            }
        // wait for prior iteration's PV reads before overwriting P tile
        asm volatile("s_waitcnt lgkmcnt(0)" ::: "memory");
        float inv[4];
        #pragma unroll
        for (int v = 0; v < 4; ++v) {
            int p = m0 + ((l >> 4) << 2) + v;
            int pc = p < 196 ? p : 195;
            int ih = pc / 14, iw = pc - ih * 14;
            int q7 = (ih >> 1) * 7 + (iw >> 1);
            float sv[4];
            float mx = -3.0e38f;
            #pragma unroll
            for (int nt = 0; nt < 4; ++nt) {
                sv[nt] = (s[nt][v] + bias7[q7 * 64 + nt * 16 + (l & 15)]) * ATT_SCALE;
                mx = fmaxf(mx, sv[nt]);
            }
            #pragma unroll
            for (int o = 8; o >= 1; o >>= 1) mx = fmaxf(mx, __shfl_xor(mx, o));
            float den = 0.f, e[4];
            #pragma unroll
            for (int nt = 0; nt < 4; ++nt) { e[nt] = __expf(sv[nt] - mx); den += e[nt]; }
            #pragma unroll
            for (int o = 8; o >= 1; o >>= 1) den += __shfl_xor(den, o);
            inv[v] = 1.f / den;
            int row = ((l >> 4) << 2) + v;
            #pragma unroll
            for (int nt = 0; nt < 4; ++nt) {
                int col = nt * 16 + (l & 15);
                *(u16*)(Pls + row * 128 + (((col >> 3) ^ (row & 7)) * 16) + ((col & 7) * 2)) = cvt_bf(e[nt]);
            }
        }
        asm volatile("s_waitcnt lgkmcnt(0)" ::: "memory");
        __builtin_amdgcn_sched_barrier(0);
        f32x4 o[8];
        #pragma unroll
        for (int nt2 = 0; nt2 < 8; ++nt2) o[nt2] = f32x4{0.f, 0.f, 0.f, 0.f};
        #pragma unroll
        for (int kk = 0; kk < 2; ++kk) {
            int rowp = l & 15;
            bf16x8 pf = *(const bf16x8*)(Pls + rowp * 128 + (((kk * 4 + (l >> 4)) ^ (rowp & 7)) * 16));
            #pragma unroll
            for (int nt2 = 0; nt2 < 8; ++nt2) {
                int d = nt2 * 16 + (l & 15);
                bf16x8 vf = *(const bf16x8*)(sm + K4_VT + d * 128 + (((kk * 4 + (l >> 4)) ^ (d & 7)) * 16));
                o[nt2] = __builtin_amdgcn_mfma_f32_16x16x32_bf16(pf, vf, o[nt2], 0, 0, 0);
            }
        }
        #pragma unroll
        for (int nt2 = 0; nt2 < 8; ++nt2) {
            #pragma unroll
            for (int v = 0; v < 4; ++v) {
                int p = m0 + ((l >> 4) << 2) + v;
                if (p < 196)
                    Ob[(size_t)p * 512 + nt2 * 16 + (l & 15)] = cvt_bf(o[nt2][v] * inv[v]);
            }
        }
    }
}

// ---------------- K5: depthwise 3x3 on bf16 attention output (NHWC, head-grouped channel order) ----------------
// bf16 LDS tile -> 14KB -> wave-cap occupancy
__global__ __launch_bounds__(256) void k5_dw2(
    const u16* __restrict__ O, const float* __restrict__ wdw,
    u16* __restrict__ z)
{
    __shared__ u16 xs[32][199];
    __shared__ float wt[32][9];
    int b = blockIdx.x >> 4, cg = blockIdx.x & 15;
    int c0 = cg * 32;
    int t = threadIdx.x;
    for (int i = t; i < 288; i += 256) {
        int cl = i / 9;
        int cp = c0 + cl;
        int corig = ((cp & 127) << 2) | (cp >> 7);
        wt[cl][i % 9] = wdw[corig * 9 + i % 9];
    }
    const u16* Ob = O + (size_t)b * 196 * 512 + c0;
    for (int i = t; i < 6272; i += 256) {
        int c = i & 31, p = i >> 5;
        xs[c][p] = Ob[(size_t)p * 512 + c];
    }
    __syncthreads();
    for (int i = t; i < 6272; i += 256) {
        int c = i & 31, p = i >> 5;
        int ii = p / 14, jj = p - ii * 14;
        float acc = 0.f;
        #pragma unroll
        for (int di = -1; di <= 1; ++di) {
            int i2 = ii + di;
            if (i2 < 0 || i2 > 13) continue;
            #pragma unroll
            for (int dj = -1; dj <= 1; ++dj) {
                int j2 = jj + dj;
                if (j2 < 0 || j2 > 13) continue;
                acc += wt[c][(di + 1) * 3 + (dj + 1)] * bf2f(xs[c][i2 * 14 + j2]);
            }
        }
        z[((size_t)b * 196 + p) * 512 + c0 + c] = cvt_bf(acc);
    }
}

extern "C" void kernel_launch(void* const* d_in, const int* in_sizes, int n_in,
                              void* d_out, int out_size, void* d_ws, size_t ws_size,
                              hipStream_t stream)
{
    const float* x    = (const float*)d_in[0];
    const float* g1   = (const float*)d_in[1];
    const float* b1   = (const float*)d_in[2];
    const float* m1   = (const float*)d_in[3];
    const float* v1   = (const float*)d_in[4];
    const float* wqdw = (const float*)d_in[5];
    const float* wqpw = (const float*)d_in[6];
    const float* rel  = (const float*)d_in[7];
    const float* wodw = (const float*)d_in[8];
    const float* wopw = (const float*)d_in[9];
    const float* g2   = (const float*)d_in[10];
    const float* b2   = (const float*)d_in[11];
    const float* m2   = (const float*)d_in[12];
    const float* v2   = (const float*)d_in[13];
    const float* wmlp = (const float*)d_in[14];

    char* ws = (char*)d_ws;
    size_t off = 0;
    auto alloc = [&](size_t bytes) { char* p = ws + off; off += (bytes + 255) & ~(size_t)255; return p; };
    u16* W1p  = (u16*)alloc(1536ull * 512 * 2);
    u16* W2p  = (u16*)alloc(512ull * 512 * 2);
    u16* W3p  = (u16*)alloc(512ull * 512 * 2);
    float* s1 = (float*)alloc(512 * 4);
    float* t1 = (float*)alloc(512 * 4);
    float* s2 = (float*)alloc(512 * 4);
    float* t2 = (float*)alloc(512 * 4);
    u16* ybf  = (u16*)alloc(25088ull * 512 * 2);   // reused later as abuf
    u16* ybil = (u16*)alloc(6272ull * 512 * 2);
    float* qbuf = (float*)alloc(25088ull * 512 * 4);   // holds qbf (bf16), reused later as resid f32
    float* kv7  = (float*)alloc(6272ull * 1024 * 4);   // holds kvbf (bf16), reused later as zbuf (bf16)
    u16* Obuf = (u16*)alloc(25088ull * 512 * 2);
    (void)ws_size; (void)in_sizes; (void)n_in; (void)out_size;

    u16* qbf  = (u16*)qbuf;
    u16* kvbf = (u16*)kv7;

    k0_prep<<<5122, 256, 0, stream>>>(wqpw, wopw, wmlp, g1, b1, m1, v1, g2, b2, m2, v2,
                                      W1p, W2p, W3p, s1, t1, s2, t2);
    k1_bn_dw_bil<<<2048, 256, 0, stream>>>(x, wqdw, s1, t1, ybf, ybil);
    gemm_tn<3><<<dim3(196, 4), 256, 0, stream>>>(ybf, W1p, nullptr, 512, nullptr, qbf, nullptr, nullptr);
    gemm_tn<3><<<dim3(49, 8), 256, 0, stream>>>(ybil, W1p + 262144, nullptr, 1024, nullptr, kvbf, nullptr, nullptr);
    k4_attn<<<512, 256, 0, stream>>>(qbf, kvbf, rel, Obuf);
    u16* zbuf = (u16*)kv7;
    k5_dw2<<<2048, 256, 0, stream>>>(Obuf, wodw, zbuf);
    float* resid = qbuf;
    u16* abuf = ybf;
    gemm_tn<1><<<dim3(196, 4), 256, 0, stream>>>(zbuf, W2p, resid, 512, x, abuf, s2, t2);
    gemm_tn<2><<<dim3(196, 4), 256, 0, stream>>>(abuf, W3p, (float*)d_out, 512, resid, nullptr, nullptr, nullptr);
}

// Round 7
// 321.659 us; speedup vs baseline: 1.3880x; 1.1153x over previous
//
#include <hip/hip_runtime.h>

typedef short bf16x8 __attribute__((ext_vector_type(8)));
typedef float f32x4 __attribute__((ext_vector_type(4)));
typedef unsigned short u16;

#define ATT_SCALE 0.08838834764831845f

__device__ __forceinline__ u16 cvt_bf(float f) {
    union { float f; unsigned u; } a; a.f = f;
    unsigned r = a.u + 0x7FFFu + ((a.u >> 16) & 1u);
    return (u16)(r >> 16);
}

__device__ __forceinline__ float bf2f(u16 h) {
    union { unsigned u; float f; } a; a.u = ((unsigned)h) << 16;
    return a.f;
}

__device__ __forceinline__ void gload_lds16(const void* g, void* l) {
    __builtin_amdgcn_global_load_lds(
        (const __attribute__((address_space(1))) unsigned int*)g,
        (__attribute__((address_space(3))) unsigned int*)l, 16, 0, 0);
}

// ---------------- K0: weight prep (permute rows/cols to head-grouped order, cvt bf16, fold BN) ----------------
__global__ __launch_bounds__(256) void k0_prep(
    const float* __restrict__ wqkv, const float* __restrict__ wout,
    const float* __restrict__ wmlp,
    const float* __restrict__ g1, const float* __restrict__ b1,
    const float* __restrict__ m1, const float* __restrict__ v1,
    const float* __restrict__ g2, const float* __restrict__ b2,
    const float* __restrict__ m2, const float* __restrict__ v2,
    u16* __restrict__ W1p, u16* __restrict__ W2p, u16* __restrict__ W3p,
    float* __restrict__ s1, float* __restrict__ t1,
    float* __restrict__ s2, float* __restrict__ t2)
{
    int idx = blockIdx.x * 256 + threadIdx.x;
    if (idx < 786432) {                       // W1p: row o' = part*512 + h*128 + d  <-  orig row part*512 + d*4 + h
        int o = idx >> 9, c = idx & 511;
        int part = o >> 9, wi = o & 511;
        int hh = wi >> 7, dd = wi & 127;
        int orig = part * 512 + dd * 4 + hh;
        W1p[idx] = cvt_bf(wqkv[orig * 512 + c]);
    } else if (idx < 1048576) {               // W2p: col c' = h*128+d  <-  orig col d*4+h
        int j = idx - 786432;
        int o = j >> 9, cp = j & 511;
        int oc = ((cp & 127) << 2) | (cp >> 7);
        W2p[j] = cvt_bf(wout[o * 512 + oc]);
    } else if (idx < 1310720) {
        int j = idx - 1048576;
        W3p[j] = cvt_bf(wmlp[j]);
    } else if (idx < 1311232) {
        int c = idx - 1310720;
        float i1 = g1[c] / sqrtf(v1[c] + 1e-5f);
        s1[c] = i1; t1[c] = b1[c] - m1[c] * i1;
        float i2 = g2[c] / sqrtf(v2[c] + 1e-5f);
        s2[c] = i2; t2[c] = b2[c] - m2[c] * i2;
    }
}

// ---------------- K1: BN1 + depthwise 3x3 + bilinear->7x7, outputs bf16 NHWC ----------------
// 448 threads = 32 ch x 14 rows. Halo-padded xs[32][16][16] bf16 (ch stride 264 u16, 16B-aligned rows):
// conv reads 3 rows as 6x ds_read_b128 into registers, 126 branch-free FMAs. ys stride 198 (99 dw == 3 mod 32,
// conflict-free cross-channel). Fixes R6's 4.08M bank conflicts (stride 199 = 99.5 dw -> 3.5c aliasing).
__global__ __launch_bounds__(448) void k1_bn_dw_bil(
    const float* __restrict__ x, const float* __restrict__ wdw,
    const float* __restrict__ s1, const float* __restrict__ t1,
    u16* __restrict__ ybf, u16* __restrict__ ybil)
{
    __shared__ __attribute__((aligned(16))) u16 xs[32 * 264];
    __shared__ u16 ys[32 * 198];
    __shared__ float wt[32][9];
    __shared__ float sc[32], tc[32];
    int b = blockIdx.x >> 4, cg = blockIdx.x & 15;
    int c0 = cg * 32;
    int t = threadIdx.x;
    if (t < 32) { sc[t] = s1[c0 + t]; tc[t] = t1[c0 + t]; }
    if (t < 288) wt[t / 9][t % 9] = wdw[(c0 + t / 9) * 9 + t % 9];
    for (int i = t; i < 4224; i += 448) ((unsigned*)xs)[i] = 0;   // zero incl. halo
    __syncthreads();
    const float4* xb4 = (const float4*)(x + ((size_t)b * 512 + c0) * 196);
    for (int i = t; i < 1568; i += 448) {     // coalesced float4; 196%4==0 so never crosses channel
        int c = i / 49, j4 = i - c * 49;
        float4 v = xb4[i];
        float ss = sc[c], tt = tc[c];
        float vv[4] = {v.x, v.y, v.z, v.w};
        #pragma unroll
        for (int k = 0; k < 4; ++k) {
            int p = 4 * j4 + k;
            int r = p / 14, jj = p - r * 14;
            xs[c * 264 + (r + 1) * 16 + (jj + 1)] = cvt_bf(vv[k] * ss + tt);
        }
    }
    __syncthreads();
    {   // conv: thread owns (channel c, output row r); all taps from registers
        int r = t >> 5, c = t & 31;
        float rowf[3][16];
        #pragma unroll
        for (int dr = 0; dr < 3; ++dr) {
            uint4 a0 = *(const uint4*)&xs[c * 264 + (r + dr) * 16];
            uint4 a1 = *(const uint4*)&xs[c * 264 + (r + dr) * 16 + 8];
            unsigned ua[8] = {a0.x, a0.y, a0.z, a0.w, a1.x, a1.y, a1.z, a1.w};
            #pragma unroll
            for (int q = 0; q < 8; ++q) {
                union { unsigned u; float f; } lo, hi;
                lo.u = ua[q] << 16; hi.u = ua[q] & 0xFFFF0000u;
                rowf[dr][2 * q] = lo.f; rowf[dr][2 * q + 1] = hi.f;
            }
        }
        float w[9];
        #pragma unroll
        for (int k = 0; k < 9; ++k) w[k] = wt[c][k];
        #pragma unroll
        for (int j = 0; j < 14; ++j) {
            float acc = 0.f;
            #pragma unroll
            for (int dr = 0; dr < 3; ++dr)
                #pragma unroll
                for (int dc = 0; dc < 3; ++dc)
                    acc += w[dr * 3 + dc] * rowf[dr][j + dc];
            ys[c * 198 + r * 14 + j] = cvt_bf(acc);
        }
    }
    __syncthreads();
    u16* yb = ybf + (size_t)b * 196 * 512 + c0;
    for (int i = t; i < 6272; i += 448) {     // coalesced NHWC store via ys
        int c = i & 31, p = i >> 5;
        yb[(size_t)p * 512 + c] = ys[c * 198 + p];
    }
    for (int i = t; i < 1568; i += 448) {     // bilinear(14->7, align_corners) pre-pointwise (linear ops commute)
        int c = i & 31, r = i >> 5;
        int ri = r / 7, rj = r - ri * 7;
        float fy = 13.f * ri / 6.f, fx = 13.f * rj / 6.f;
        int y0 = (int)fy; int y1 = min(y0 + 1, 13);
        int x0 = (int)fx; int x1 = min(x0 + 1, 13);
        float wy = fy - y0, wx = fx - x0;
        float v00 = bf2f(ys[c * 198 + y0 * 14 + x0]), v01 = bf2f(ys[c * 198 + y0 * 14 + x1]);
        float v10 = bf2f(ys[c * 198 + y1 * 14 + x0]), v11 = bf2f(ys[c * 198 + y1 * 14 + x1]);
        float top = v00 + (v01 - v00) * wx;
        float bot = v10 + (v11 - v10) * wx;
        float r7  = top + (bot - top) * wy;
        ybil[((size_t)b * 49 + r) * 512 + c0 + c] = cvt_bf(r7);
    }
}

// ---------------- GEMM: C[row][col] = sum_k A[row][k]*B[col][k], A/B bf16 K-contig, 128x128 tile, BK=32 ----------------
// EPI 0: plain f32 store [row*ldo+col]
// EPI 1: +x (NCHW) -> resid f32 [row*512+col]; a = relu(bn2(resid)) -> bf16 [row*512+col]
// EPI 2: +resid f32 [row*512+col] -> NCHW f32 store (final output)
// EPI 3: bf16 store [row*ldo+col] into auxb
template<int EPI>
__global__ __launch_bounds__(256, 2) void gemm_tn(
    const u16* __restrict__ A, const u16* __restrict__ Bw,
    float* __restrict__ out, int ldo,
    const float* __restrict__ auxf, u16* __restrict__ auxb,
    const float* __restrict__ s2, const float* __restrict__ t2)
{
    __shared__ __attribute__((aligned(16))) char smA[8192];
    __shared__ __attribute__((aligned(16))) char smB[8192];
    int t = threadIdx.x;
    int wv = t >> 6, l = t & 63;
    int wr = wv >> 1, wc = wv & 1;
    int m0 = blockIdx.x * 128, n0 = blockIdx.y * 128;
    f32x4 acc[4][4];
    #pragma unroll
    for (int mi = 0; mi < 4; ++mi)
        #pragma unroll
        for (int ni = 0; ni < 4; ++ni)
            acc[mi][ni] = f32x4{0.f, 0.f, 0.f, 0.f};

    const char* Ag = (const char*)A + (size_t)(m0 + (t >> 2)) * 1024 + ((t & 3) << 4);
    const char* Bg = (const char*)Bw + (size_t)(n0 + (t >> 2)) * 1024 + ((t & 3) << 4);
    char* lA = smA + wv * 1024;
    char* lB = smB + wv * 1024;
    int kb = (l >> 4) << 4;
    int rA = wr * 64 + (l & 15);
    int rB = wc * 64 + (l & 15);

    for (int kt = 0; kt < 16; ++kt) {
        __syncthreads();
        gload_lds16(Ag, lA);
        gload_lds16(Ag + 65536, lA + 4096);
        gload_lds16(Bg, lB);
        gload_lds16(Bg + 65536, lB + 4096);
        Ag += 64; Bg += 64;
        __syncthreads();
        bf16x8 af[4], bfr[4];
        #pragma unroll
        for (int mi = 0; mi < 4; ++mi)
            af[mi] = *(const bf16x8*)(smA + (rA + mi * 16) * 64 + kb);
        #pragma unroll
        for (int ni = 0; ni < 4; ++ni)
            bfr[ni] = *(const bf16x8*)(smB + (rB + ni * 16) * 64 + kb);
        #pragma unroll
        for (int mi = 0; mi < 4; ++mi)
            #pragma unroll
            for (int ni = 0; ni < 4; ++ni)
                acc[mi][ni] = __builtin_amdgcn_mfma_f32_16x16x32_bf16(af[mi], bfr[ni], acc[mi][ni], 0, 0, 0);
    }

    #pragma unroll
    for (int mi = 0; mi < 4; ++mi) {
        int rowg = m0 + wr * 64 + mi * 16 + ((l >> 4) << 2);   // 4 consecutive rows; 196%4==0 so never crosses a batch image
        if (EPI == 0) {
            #pragma unroll
            for (int ni = 0; ni < 4; ++ni) {
                int colg = n0 + wc * 64 + ni * 16 + (l & 15);
                float* op = out + (size_t)rowg * ldo + colg;
                #pragma unroll
                for (int v = 0; v < 4; ++v) op[(size_t)v * ldo] = acc[mi][ni][v];
            }
        } else if (EPI == 3) {
            #pragma unroll
            for (int ni = 0; ni < 4; ++ni) {
                int colg = n0 + wc * 64 + ni * 16 + (l & 15);
                #pragma unroll
                for (int v = 0; v < 4; ++v)
                    auxb[(size_t)(rowg + v) * ldo + colg] = cvt_bf(acc[mi][ni][v]);
            }
        } else if (EPI == 1) {
            int bb = rowg / 196, pp = rowg - bb * 196;
            #pragma unroll
            for (int ni = 0; ni < 4; ++ni) {
                int colg = n0 + wc * 64 + ni * 16 + (l & 15);
                float4 xv = *(const float4*)(auxf + (size_t)bb * 100352 + (size_t)colg * 196 + pp);
                const float* xa = (const float*)&xv;
                float ss = s2[colg], tt = t2[colg];
                #pragma unroll
                for (int v = 0; v < 4; ++v) {
                    float rv = acc[mi][ni][v] + xa[v];
                    out[(size_t)(rowg + v) * 512 + colg] = rv;
                    float av = rv * ss + tt;
                    av = av > 0.f ? av : 0.f;
                    auxb[(size_t)(rowg + v) * 512 + colg] = cvt_bf(av);
                }
            }
        } else {
            int bb = rowg / 196, pp = rowg - bb * 196;
            #pragma unroll
            for (int ni = 0; ni < 4; ++ni) {
                int colg = n0 + wc * 64 + ni * 16 + (l & 15);
                float4 dv;
                float* da = (float*)&dv;
                #pragma unroll
                for (int v = 0; v < 4; ++v)
                    da[v] = acc[mi][ni][v] + auxf[(size_t)(rowg + v) * 512 + colg];
                *(float4*)(out + (size_t)bb * 100352 + (size_t)colg * 196 + pp) = dv;
            }
        }
    }
}

// ---------------- K4: MFMA attention per (b,h): softmax((QK^T + bias)*scale) V, bf16 O output ----------------
// LDS layout (bytes):
//   [0, 16384)      Kls[64][128] bf16, 16B chunks swizzled: chunk' = chunk ^ (row&15)
//   [16384, 32768)  Vt[128][64]  bf16 (d-major), chunks swizzled: chunk' = chunk ^ (d&7)
//   [32768, 45312)  bias7[49][64] f32 (cols >=49 = -1e30 mask)
//   [45312, 61696)  staging Vtmp[64][128] bf16 (row-major), later per-wave P tiles (2KB each)
#define K4_KLS   0
#define K4_VT    16384
#define K4_BIAS  32768
#define K4_SHR   45312
__global__ __launch_bounds__(256) void k4_attn(
    const u16* __restrict__ qbf, const u16* __restrict__ kvbf,
    const float* __restrict__ rel, u16* __restrict__ O)
{
    __shared__ __attribute__((aligned(16))) char sm[61696];
    int b = blockIdx.x >> 2, h = blockIdx.x & 3;
    int t = threadIdx.x, w = t >> 6, l = t & 63;
    const char* kvbase = (const char*)(kvbf + (size_t)b * 49 * 1024 + h * 128);
    // stage K (swizzled) + V (row-major), zero-pad rows 49..63
    for (int id = t; id < 1024; id += 256) {
        int r = id >> 4, c = id & 15;
        uint4 kvv = make_uint4(0, 0, 0, 0), vvv = make_uint4(0, 0, 0, 0);
        if (r < 49) {
            kvv = *(const uint4*)(kvbase + (size_t)r * 2048 + c * 16);
            vvv = *(const uint4*)(kvbase + (size_t)r * 2048 + 1024 + c * 16);
        }
        *(uint4*)(sm + K4_KLS + r * 256 + ((c ^ (r & 15)) * 16)) = kvv;
        *(uint4*)(sm + K4_SHR + r * 256 + c * 16) = vvv;
    }
    float* bias7 = (float*)(sm + K4_BIAS);
    for (int id = t; id < 3136; id += 256) {
        int q7 = id >> 6, j = id & 63;
        float bv = -1e30f;
        if (j < 49) {
            int ki = j / 7, kj = j - ki * 7;
            int qi = q7 / 7, qj = q7 - qi * 7;
            bv = rel[((qi - ki + 6) * 13 + (qj - kj + 6)) * 4 + h];
        }
        bias7[id] = bv;
    }
    __syncthreads();
    // LDS transpose: Vtmp[64][128] -> Vt[128][64] (bf16), lane-consecutive d for conflict-free access
    for (int li = 0; li < 4; ++li) {
        int id = li * 256 + t;
        int d = id & 127, jc = id >> 7;
        u16 vals[8];
        #pragma unroll
        for (int i = 0; i < 8; ++i)
            vals[i] = *(const u16*)(sm + K4_SHR + (jc * 8 + i) * 256 + d * 2);
        *(uint4*)(sm + K4_VT + d * 128 + ((jc ^ (d & 7)) * 16)) = *(uint4*)vals;
    }
    __syncthreads();
    const u16* qb = qbf + (size_t)b * 196 * 512 + h * 128;
    u16* Ob = O + (size_t)b * 196 * 512 + h * 128;
    char* Pls = sm + K4_SHR + w * 2048;     // per-wave 16x64 bf16 P tile, chunk ^= (row&7)
    for (int mt = w; mt < 13; mt += 4) {
        int m0 = mt * 16;
        int pa = m0 + (l & 15);
        const u16* qrow = qb + (size_t)pa * 512 + ((l >> 4) << 3);
        bf16x8 qf[4];
        #pragma unroll
        for (int kk = 0; kk < 4; ++kk) {
            bf16x8 z = {0, 0, 0, 0, 0, 0, 0, 0};
            qf[kk] = (pa < 196) ? *(const bf16x8*)(qrow + kk * 32) : z;
        }
        f32x4 s[4];
        #pragma unroll
        for (int nt = 0; nt < 4; ++nt) s[nt] = f32x4{0.f, 0.f, 0.f, 0.f};
        #pragma unroll
        for (int kk = 0; kk < 4; ++kk)
            #pragma unroll
            for (int nt = 0; nt < 4; ++nt) {
                int row = nt * 16 + (l & 15);
                bf16x8 kf = *(const bf16x8*)(sm + K4_KLS + row * 256 + (((kk * 4 + (l >> 4)) ^ (row & 15)) * 16));
                s[nt] = __builtin_amdgcn_mfma_f32_16x16x32_bf16(qf[kk], kf, s[nt], 0, 0, 0);
            }
        // wait for prior iteration's PV reads before overwriting P tile
        asm volatile("s_waitcnt lgkmcnt(0)" ::: "memory");
        float inv[4];
        #pragma unroll
        for (int v = 0; v < 4; ++v) {
            int p = m0 + ((l >> 4) << 2) + v;
            int pc = p < 196 ? p : 195;
            int ih = pc / 14, iw = pc - ih * 14;
            int q7 = (ih >> 1) * 7 + (iw >> 1);
            float sv[4];
            float mx = -3.0e38f;
            #pragma unroll
            for (int nt = 0; nt < 4; ++nt) {
                sv[nt] = (s[nt][v] + bias7[q7 * 64 + nt * 16 + (l & 15)]) * ATT_SCALE;
                mx = fmaxf(mx, sv[nt]);
            }
            #pragma unroll
            for (int o = 8; o >= 1; o >>= 1) mx = fmaxf(mx, __shfl_xor(mx, o));
            float den = 0.f, e[4];
            #pragma unroll
            for (int nt = 0; nt < 4; ++nt) { e[nt] = __expf(sv[nt] - mx); den += e[nt]; }
            #pragma unroll
            for (int o = 8; o >= 1; o >>= 1) den += __shfl_xor(den, o);
            inv[v] = 1.f / den;
            int row = ((l >> 4) << 2) + v;
            #pragma unroll
            for (int nt = 0; nt < 4; ++nt) {
                int col = nt * 16 + (l & 15);
                *(u16*)(Pls + row * 128 + (((col >> 3) ^ (row & 7)) * 16) + ((col & 7) * 2)) = cvt_bf(e[nt]);
            }
        }
        asm volatile("s_waitcnt lgkmcnt(0)" ::: "memory");
        __builtin_amdgcn_sched_barrier(0);
        f32x4 o[8];
        #pragma unroll
        for (int nt2 = 0; nt2 < 8; ++nt2) o[nt2] = f32x4{0.f, 0.f, 0.f, 0.f};
        #pragma unroll
        for (int kk = 0; kk < 2; ++kk) {
            int rowp = l & 15;
            bf16x8 pf = *(const bf16x8*)(Pls + rowp * 128 + (((kk * 4 + (l >> 4)) ^ (rowp & 7)) * 16));
            #pragma unroll
            for (int nt2 = 0; nt2 < 8; ++nt2) {
                int d = nt2 * 16 + (l & 15);
                bf16x8 vf = *(const bf16x8*)(sm + K4_VT + d * 128 + (((kk * 4 + (l >> 4)) ^ (d & 7)) * 16));
                o[nt2] = __builtin_amdgcn_mfma_f32_16x16x32_bf16(pf, vf, o[nt2], 0, 0, 0);
            }
        }
        #pragma unroll
        for (int nt2 = 0; nt2 < 8; ++nt2) {
            #pragma unroll
            for (int v = 0; v < 4; ++v) {
                int p = m0 + ((l >> 4) << 2) + v;
                if (p < 196)
                    Ob[(size_t)p * 512 + nt2 * 16 + (l & 15)] = cvt_bf(o[nt2][v] * inv[v]);
            }
        }
    }
}

// ---------------- K5: depthwise 3x3 on bf16 attention output (NHWC, head-grouped channel order) ----------------
// Same register-row halo structure as K1.
__global__ __launch_bounds__(448) void k5_dw2(
    const u16* __restrict__ O, const float* __restrict__ wdw,
    u16* __restrict__ z)
{
    __shared__ __attribute__((aligned(16))) u16 xs[32 * 264];
    __shared__ u16 ys[32 * 198];
    __shared__ float wt[32][9];
    int b = blockIdx.x >> 4, cg = blockIdx.x & 15;
    int c0 = cg * 32;
    int t = threadIdx.x;
    if (t < 288) {
        int cl = t / 9;
        int cp = c0 + cl;
        int corig = ((cp & 127) << 2) | (cp >> 7);
        wt[cl][t % 9] = wdw[corig * 9 + t % 9];
    }
    for (int i = t; i < 4224; i += 448) ((unsigned*)xs)[i] = 0;
    __syncthreads();
    const u16* Ob = O + (size_t)b * 196 * 512 + c0;
    for (int i = t; i < 784; i += 448) {      // coalesced 16B reads (4 lanes = 64B line), scatter to halo tile
        int p = i >> 2, c8 = i & 3;
        uint4 v = *(const uint4*)&Ob[(size_t)p * 512 + c8 * 8];
        int r = p / 14, jj = p - r * 14;
        u16 tmp[8]; *(uint4*)tmp = v;
        #pragma unroll
        for (int k = 0; k < 8; ++k)
            xs[(c8 * 8 + k) * 264 + (r + 1) * 16 + (jj + 1)] = tmp[k];
    }
    __syncthreads();
    {
        int r = t >> 5, c = t & 31;
        float rowf[3][16];
        #pragma unroll
        for (int dr = 0; dr < 3; ++dr) {
            uint4 a0 = *(const uint4*)&xs[c * 264 + (r + dr) * 16];
            uint4 a1 = *(const uint4*)&xs[c * 264 + (r + dr) * 16 + 8];
            unsigned ua[8] = {a0.x, a0.y, a0.z, a0.w, a1.x, a1.y, a1.z, a1.w};
            #pragma unroll
            for (int q = 0; q < 8; ++q) {
                union { unsigned u; float f; } lo, hi;
                lo.u = ua[q] << 16; hi.u = ua[q] & 0xFFFF0000u;
                rowf[dr][2 * q] = lo.f; rowf[dr][2 * q + 1] = hi.f;
            }
        }
        float w[9];
        #pragma unroll
        for (int k = 0; k < 9; ++k) w[k] = wt[c][k];
        #pragma unroll
        for (int j = 0; j < 14; ++j) {
            float acc = 0.f;
            #pragma unroll
            for (int dr = 0; dr < 3; ++dr)
                #pragma unroll
                for (int dc = 0; dc < 3; ++dc)
                    acc += w[dr * 3 + dc] * rowf[dr][j + dc];
            ys[c * 198 + r * 14 + j] = cvt_bf(acc);
        }
    }
    __syncthreads();
    u16* zb = z + (size_t)b * 196 * 512 + c0;
    for (int i = t; i < 6272; i += 448) {
        int c = i & 31, p = i >> 5;
        zb[(size_t)p * 512 + c] = ys[c * 198 + p];
    }
}

extern "C" void kernel_launch(void* const* d_in, const int* in_sizes, int n_in,
                              void* d_out, int out_size, void* d_ws, size_t ws_size,
                              hipStream_t stream)
{
    const float* x    = (const float*)d_in[0];
    const float* g1   = (const float*)d_in[1];
    const float* b1   = (const float*)d_in[2];
    const float* m1   = (const float*)d_in[3];
    const float* v1   = (const float*)d_in[4];
    const float* wqdw = (const float*)d_in[5];
    const float* wqpw = (const float*)d_in[6];
    const float* rel  = (const float*)d_in[7];
    const float* wodw = (const float*)d_in[8];
    const float* wopw = (const float*)d_in[9];
    const float* g2   = (const float*)d_in[10];
    const float* b2   = (const float*)d_in[11];
    const float* m2   = (const float*)d_in[12];
    const float* v2   = (const float*)d_in[13];
    const float* wmlp = (const float*)d_in[14];

    char* ws = (char*)d_ws;
    size_t off = 0;
    auto alloc = [&](size_t bytes) { char* p = ws + off; off += (bytes + 255) & ~(size_t)255; return p; };
    u16* W1p  = (u16*)alloc(1536ull * 512 * 2);
    u16* W2p  = (u16*)alloc(512ull * 512 * 2);
    u16* W3p  = (u16*)alloc(512ull * 512 * 2);
    float* s1 = (float*)alloc(512 * 4);
    float* t1 = (float*)alloc(512 * 4);
    float* s2 = (float*)alloc(512 * 4);
    float* t2 = (float*)alloc(512 * 4);
    u16* ybf  = (u16*)alloc(25088ull * 512 * 2);   // reused later as abuf
    u16* ybil = (u16*)alloc(6272ull * 512 * 2);
    float* qbuf = (float*)alloc(25088ull * 512 * 4);   // holds qbf (bf16), reused later as resid f32
    float* kv7  = (float*)alloc(6272ull * 1024 * 4);   // holds kvbf (bf16), reused later as zbuf (bf16)
    u16* Obuf = (u16*)alloc(25088ull * 512 * 2);
    (void)ws_size; (void)in_sizes; (void)n_in; (void)out_size;

    u16* qbf  = (u16*)qbuf;
    u16* kvbf = (u16*)kv7;

    k0_prep<<<5122, 256, 0, stream>>>(wqpw, wopw, wmlp, g1, b1, m1, v1, g2, b2, m2, v2,
                                      W1p, W2p, W3p, s1, t1, s2, t2);
    k1_bn_dw_bil<<<2048, 448, 0, stream>>>(x, wqdw, s1, t1, ybf, ybil);
    gemm_tn<3><<<dim3(196, 4), 256, 0, stream>>>(ybf, W1p, nullptr, 512, nullptr, qbf, nullptr, nullptr);
    gemm_tn<3><<<dim3(49, 8), 256, 0, stream>>>(ybil, W1p + 262144, nullptr, 1024, nullptr, kvbf, nullptr, nullptr);
    k4_attn<<<512, 256, 0, stream>>>(qbf, kvbf, rel, Obuf);
    u16* zbuf = (u16*)kv7;
    k5_dw2<<<2048, 448, 0, stream>>>(Obuf, wodw, zbuf);
    float* resid = qbuf;
    u16* abuf = ybf;
    gemm_tn<1><<<dim3(196, 4), 256, 0, stream>>>(zbuf, W2p, resid, 512, x, abuf, s2, t2);
    gemm_tn<2><<<dim3(196, 4), 256, 0, stream>>>(abuf, W3p, (float*)d_out, 512, resid, nullptr, nullptr, nullptr);
}